// Round 2
// baseline (354.161 us; speedup 1.0000x reference)
//
#include <hip/hip_runtime.h>
#include <hip/hip_bf16.h>

typedef __attribute__((ext_vector_type(8))) short short8;
typedef __attribute__((ext_vector_type(4))) float f32x4;
typedef __attribute__((ext_vector_type(4))) unsigned short u16x4;
typedef __attribute__((ext_vector_type(4))) int int4v;

#define DEVI static __device__ __forceinline__

constexpr int B_ = 4, S_ = 2048, D_ = 768, NH_ = 12, DH_ = 64;
constexpr int M_ = B_ * S_;                 // 8192
constexpr size_t NX = (size_t)M_ * D_;      // 6291456 elems
constexpr size_t NW = (size_t)D_ * D_;      // 589824 elems

DEVI unsigned short f2bf(float f) {
  union { float f; unsigned u; } c; c.f = f;
  unsigned u = c.u;
  return (unsigned short)((u + 0x7FFFu + ((u >> 16) & 1u)) >> 16);  // RNE
}

DEVI void gload16(const void* g, void* l) {
  __builtin_amdgcn_global_load_lds(
      (const __attribute__((address_space(1))) void*)g,
      (__attribute__((address_space(3))) void*)l, 16, 0, 0);
}

// ---------------------------------------------------------------- convert
// segs 0-2: X (NX bf16), 3-6: W (NW bf16), 7: mask int -> f32 addend table
__global__ __launch_bounds__(256) void convert_kernel(
    const float* __restrict__ s0, const float* __restrict__ s1,
    const float* __restrict__ s2, const float* __restrict__ s3,
    const float* __restrict__ s4, const float* __restrict__ s5,
    const float* __restrict__ s6, const int* __restrict__ smask,
    unsigned short* __restrict__ d0, unsigned short* __restrict__ d1,
    unsigned short* __restrict__ d2, unsigned short* __restrict__ d3,
    unsigned short* __restrict__ d4, unsigned short* __restrict__ d5,
    unsigned short* __restrict__ d6, float* __restrict__ dmask) {
  int seg = blockIdx.y;
  long i = (long)blockIdx.x * 256 + threadIdx.x;
  if (seg == 7) {
    if (i * 4 >= (long)B_ * S_) return;
    int4v m = *(const int4v*)(smask + i * 4);
    f32x4 o;
    o.x = m.x ? 0.f : -1e30f; o.y = m.y ? 0.f : -1e30f;
    o.z = m.z ? 0.f : -1e30f; o.w = m.w ? 0.f : -1e30f;
    *(f32x4*)(dmask + i * 4) = o;
    return;
  }
  const float* src; unsigned short* dst; long n;
  switch (seg) {
    case 0: src = s0; dst = d0; n = (long)NX; break;
    case 1: src = s1; dst = d1; n = (long)NX; break;
    case 2: src = s2; dst = d2; n = (long)NX; break;
    case 3: src = s3; dst = d3; n = (long)NW; break;
    case 4: src = s4; dst = d4; n = (long)NW; break;
    case 5: src = s5; dst = d5; n = (long)NW; break;
    default: src = s6; dst = d6; n = (long)NW; break;
  }
  if (i * 4 >= n) return;
  f32x4 v = *(const f32x4*)(src + i * 4);
  u16x4 o;
  o.x = f2bf(v.x); o.y = f2bf(v.y); o.z = f2bf(v.z); o.w = f2bf(v.w);
  *(u16x4*)(dst + i * 4) = o;
}

// ---------------------------------------------------------------- gemm core
// C[128x128] tile of A[M,768] @ Bt[768,768]^T, bf16 MFMA 16x16x32.
// 4 waves, each 64x64 (4x4 fragments). BK=32, global_load_lds staging.
DEVI void gemm_core(const unsigned short* __restrict__ A,
                    const unsigned short* __restrict__ Bt,
                    unsigned short* As, unsigned short* Bs,
                    int m0, int n0, int tid, f32x4 acc[4][4]) {
  const int w = tid >> 6, l = tid & 63;
  const int wm = w >> 1, wn = w & 1;
  const int lr = l & 15, lg = l >> 4;

  const unsigned short* gA0 = A  + (size_t)(m0 + (tid >> 2)) * 768 + (tid & 3) * 8;
  const unsigned short* gB0 = Bt + (size_t)(n0 + (tid >> 2)) * 768 + (tid & 3) * 8;
  unsigned short* lA0 = As + (size_t)(w * 64) * 8;  // wave-uniform LDS base
  unsigned short* lB0 = Bs + (size_t)(w * 64) * 8;
  const unsigned short* fA = As + (size_t)(wm * 64 + lr) * 32 + lg * 8;
  const unsigned short* fB = Bs + (size_t)(wn * 64 + lr) * 32 + lg * 8;

  for (int k0 = 0; k0 < 768; k0 += 32) {
    __syncthreads();
    gload16(gA0 + k0, lA0);
    gload16(gA0 + (size_t)64 * 768 + k0, lA0 + 2048);
    gload16(gB0 + k0, lB0);
    gload16(gB0 + (size_t)64 * 768 + k0, lB0 + 2048);
    __syncthreads();
    short8 af[4], bf[4];
#pragma unroll
    for (int m = 0; m < 4; m++) af[m] = *(const short8*)(fA + m * 16 * 32);
#pragma unroll
    for (int n = 0; n < 4; n++) bf[n] = *(const short8*)(fB + n * 16 * 32);
#pragma unroll
    for (int m = 0; m < 4; m++)
#pragma unroll
      for (int n = 0; n < 4; n++)
        acc[m][n] = __builtin_amdgcn_mfma_f32_16x16x32_bf16(af[m], bf[n], acc[m][n], 0, 0, 0);
  }
}

// ---------------------------------------------------------------- QKV gemm
__global__ __launch_bounds__(256) void qkv_gemm(
    const unsigned short* __restrict__ Xq, const unsigned short* __restrict__ Xk,
    const unsigned short* __restrict__ Xv,
    const unsigned short* __restrict__ Wq, const unsigned short* __restrict__ Wk,
    const unsigned short* __restrict__ Wv,
    const float* __restrict__ bq, const float* __restrict__ bk,
    const float* __restrict__ bv,
    unsigned short* __restrict__ Oq, unsigned short* __restrict__ Ok,
    unsigned short* __restrict__ Ov) {
  __shared__ unsigned short As[128 * 32], Bs[128 * 32];
  const int z = blockIdx.z;
  const unsigned short* A  = (z == 0) ? Xq : (z == 1) ? Xk : Xv;
  const unsigned short* Bt = (z == 0) ? Wq : (z == 1) ? Wk : Wv;
  const float* bias        = (z == 0) ? bq : (z == 1) ? bk : bv;
  unsigned short* O        = (z == 0) ? Oq : (z == 1) ? Ok : Ov;
  const float scale = (z == 0) ? 0.125f : 1.0f;

  const int m0 = blockIdx.x * 128, n0 = blockIdx.y * 128;
  f32x4 acc[4][4] = {};
  gemm_core(A, Bt, As, Bs, m0, n0, threadIdx.x, acc);

  const int tid = threadIdx.x, w = tid >> 6, l = tid & 63;
  const int wm = w >> 1, wn = w & 1, lr = l & 15, lg = l >> 4;
#pragma unroll
  for (int n = 0; n < 4; n++) {
    const int ng = n0 + wn * 64 + n * 16 + lr;
    const float bvv = bias[ng];
    const int h = ng >> 6, d = ng & 63;
#pragma unroll
    for (int m = 0; m < 4; m++) {
#pragma unroll
      for (int r = 0; r < 4; r++) {
        const int mg = m0 + wm * 64 + m * 16 + lg * 4 + r;
        const int b = mg >> 11, s = mg & 2047;
        O[((size_t)(b * NH_ + h) * S_ + s) * DH_ + d] = f2bf((acc[m][n][r] + bvv) * scale);
      }
    }
  }
}

// ---------------------------------------------------------------- out gemm
__global__ __launch_bounds__(256) void out_gemm(
    const unsigned short* __restrict__ A, const unsigned short* __restrict__ Bt,
    const float* __restrict__ bias, float* __restrict__ out) {
  __shared__ unsigned short As[128 * 32], Bs[128 * 32];
  const int m0 = blockIdx.x * 128, n0 = blockIdx.y * 128;
  f32x4 acc[4][4] = {};
  gemm_core(A, Bt, As, Bs, m0, n0, threadIdx.x, acc);

  const int tid = threadIdx.x, w = tid >> 6, l = tid & 63;
  const int wm = w >> 1, wn = w & 1, lr = l & 15, lg = l >> 4;
#pragma unroll
  for (int n = 0; n < 4; n++) {
    const int ng = n0 + wn * 64 + n * 16 + lr;
    const float bvv = bias[ng];
#pragma unroll
    for (int m = 0; m < 4; m++) {
#pragma unroll
      for (int r = 0; r < 4; r++) {
        const int mg = m0 + wm * 64 + m * 16 + lg * 4 + r;
        out[(size_t)mg * 768 + ng] = acc[m][n][r] + bvv;
      }
    }
  }
}

// ---------------------------------------------------------------- V transpose
// Vp[B,H,S,D] -> Vt[B,H,D,S], per (b,h): [2048][64] -> [64][2048]
__global__ __launch_bounds__(256) void transpose_v(
    const unsigned short* __restrict__ Vp, unsigned short* __restrict__ Vt) {
  __shared__ unsigned short T[64 * 72];
  const int bh = blockIdx.y;
  const int s0 = blockIdx.x * 64;
  const int t = threadIdx.x;
  const int rl = t >> 3, u = t & 7;
#pragma unroll
  for (int i = 0; i < 2; i++) {
    const int s = rl + i * 32;
    short8 v = *(const short8*)&Vp[((size_t)bh * S_ + s0 + s) * DH_ + u * 8];
#pragma unroll
    for (int j = 0; j < 8; j++) T[(u * 8 + j) * 72 + s] = (unsigned short)v[j];
  }
  __syncthreads();
#pragma unroll
  for (int i = 0; i < 2; i++) {
    const int d = rl + i * 32;
    short8 o = *(const short8*)&T[d * 72 + u * 8];
    *(short8*)&Vt[((size_t)bh * DH_ + d) * S_ + s0 + u * 8] = o;
  }
}

// ---------------------------------------------------------------- attention
// Swapped-QK^T flash attention. 4 waves x 32 q-rows = 128 q/block.
// KV tile = 64 keys, K/V read directly from global (L2-resident), no barriers.
// S^T = K.Q via mfma(A=K,B=Q): lane lr holds scores for q=lr -> softmax is
// 15 local fmax/add + 2 shfl_xor. P re-layout through per-wave LDS buffer.
__global__ __launch_bounds__(256) void attn_kernel(
    const unsigned short* __restrict__ Qp, const unsigned short* __restrict__ Kp,
    const unsigned short* __restrict__ Vt, const float* __restrict__ maskadd,
    unsigned short* __restrict__ Ctx) {
  __shared__ unsigned short Ps[4][2][16][72];  // [wave][qb][q][key(+pad)]

  const int bh = blockIdx.y, b = bh / NH_, h = bh % NH_;
  const int tid = threadIdx.x, w = tid >> 6, l = tid & 63;
  const int lr = l & 15, lg = l >> 4;
  const int qw = blockIdx.x * 128 + w * 32;

  // Q fragments (B-operand of S^T): lane lr = q, k-dim = d = lg*8 + ks*32
  short8 aq[2][2];
#pragma unroll
  for (int qb = 0; qb < 2; qb++)
#pragma unroll
    for (int ks = 0; ks < 2; ks++)
      aq[qb][ks] = *(const short8*)&Qp[((size_t)bh * S_ + qw + qb * 16 + lr) * DH_ +
                                       lg * 8 + ks * 32];

  const unsigned short* Kb = Kp + ((size_t)bh * S_ + lr) * DH_ + lg * 8;
  const unsigned short* Vb = Vt + ((size_t)bh * DH_ + lr) * (size_t)S_ + lg * 8;
  const float* Mb = maskadd + b * S_ + lg * 4;

  float m_run[2], l_run[2];
  f32x4 ctx[2][4] = {};
#pragma unroll
  for (int qb = 0; qb < 2; qb++) { m_run[qb] = -INFINITY; l_run[qb] = 0.f; }

  unsigned short* PwBase = &Ps[w][0][0][0];

  for (int kt = 0; kt < S_ / 64; kt++) {
    const int kv0 = kt * 64;

    // ---- S^T = K.Q : 16 MFMAs, K-frags straight from global
    f32x4 sacc[2][4] = {};
    __builtin_amdgcn_s_setprio(1);
#pragma unroll
    for (int t = 0; t < 4; t++) {
      const unsigned short* kp = Kb + (size_t)(kv0 + 16 * t) * DH_;
      short8 kf0 = *(const short8*)(kp);
      short8 kf1 = *(const short8*)(kp + 32);
      sacc[0][t] = __builtin_amdgcn_mfma_f32_16x16x32_bf16(kf0, aq[0][0], sacc[0][t], 0, 0, 0);
      sacc[0][t] = __builtin_amdgcn_mfma_f32_16x16x32_bf16(kf1, aq[0][1], sacc[0][t], 0, 0, 0);
      sacc[1][t] = __builtin_amdgcn_mfma_f32_16x16x32_bf16(kf0, aq[1][0], sacc[1][t], 0, 0, 0);
      sacc[1][t] = __builtin_amdgcn_mfma_f32_16x16x32_bf16(kf1, aq[1][1], sacc[1][t], 0, 0, 0);
    }
    __builtin_amdgcn_s_setprio(0);

    // ---- mask addend (row = key = 16t + lg*4 + r)
#pragma unroll
    for (int t = 0; t < 4; t++) {
      f32x4 mk = *(const f32x4*)(Mb + kv0 + 16 * t);
#pragma unroll
      for (int r = 0; r < 4; r++) { sacc[0][t][r] += mk[r]; sacc[1][t][r] += mk[r]; }
    }

    // ---- V fragments (B-operand of PV), shared by both q sub-blocks
    short8 vf[4][2];
#pragma unroll
    for (int dt = 0; dt < 4; dt++)
#pragma unroll
      for (int ks = 0; ks < 2; ks++)
        vf[dt][ks] = *(const short8*)(Vb + (size_t)(16 * dt) * S_ + kv0 + ks * 32);

#pragma unroll
    for (int qb = 0; qb < 2; qb++) {
      // ---- online softmax for q = lr (16 values per lane: t x r)
      float mx = sacc[qb][0][0];
#pragma unroll
      for (int t = 0; t < 4; t++)
#pragma unroll
        for (int r = 0; r < 4; r++)
          if (t || r) mx = fmaxf(mx, sacc[qb][t][r]);
      mx = fmaxf(mx, __shfl_xor(mx, 16));
      mx = fmaxf(mx, __shfl_xor(mx, 32));
      const float nm = fmaxf(m_run[qb], mx);
      const float al = __expf(m_run[qb] - nm);
      m_run[qb] = nm;
      float ts = 0.f;
#pragma unroll
      for (int t = 0; t < 4; t++)
#pragma unroll
        for (int r = 0; r < 4; r++) {
          const float p = __expf(sacc[qb][t][r] - nm);
          sacc[qb][t][r] = p; ts += p;
        }
      ts += __shfl_xor(ts, 16);
      ts += __shfl_xor(ts, 32);
      l_run[qb] = l_run[qb] * al + ts;

      // ---- store P[q=lr][key] (u16x4 per tile), per-wave buffer, no barrier
      unsigned short* pr = PwBase + ((size_t)qb * 16 + lr) * 72 + lg * 4;
#pragma unroll
      for (int t = 0; t < 4; t++) {
        u16x4 pk;
#pragma unroll
        for (int r = 0; r < 4; r++) pk[r] = f2bf(sacc[qb][t][r]);
        *(u16x4*)(pr + 16 * t) = pk;
      }

      // ---- rescale ctx by alpha (broadcast from lane lr = q = lg*4+r)
      float av[4];
#pragma unroll
      for (int r = 0; r < 4; r++) av[r] = __shfl(al, lg * 4 + r, 16);
#pragma unroll
      for (int dt = 0; dt < 4; dt++)
#pragma unroll
        for (int r = 0; r < 4; r++) ctx[qb][dt][r] *= av[r];

      // ---- PV: A = P (lane lr = q, k = key), B = Vt fragment
      const unsigned short* pb = PwBase + ((size_t)qb * 16 + lr) * 72;
      short8 pa0 = *(const short8*)(pb + lg * 8);
      short8 pa1 = *(const short8*)(pb + lg * 8 + 32);
      __builtin_amdgcn_s_setprio(1);
#pragma unroll
      for (int dt = 0; dt < 4; dt++) {
        ctx[qb][dt] = __builtin_amdgcn_mfma_f32_16x16x32_bf16(pa0, vf[dt][0], ctx[qb][dt], 0, 0, 0);
        ctx[qb][dt] = __builtin_amdgcn_mfma_f32_16x16x32_bf16(pa1, vf[dt][1], ctx[qb][dt], 0, 0, 0);
      }
      __builtin_amdgcn_s_setprio(0);
    }
  }

  // ---- epilogue: normalize (1/l broadcast like alpha), write bf16 ctx
#pragma unroll
  for (int qb = 0; qb < 2; qb++) {
    const float linv = 1.f / l_run[qb];
    float iv[4];
#pragma unroll
    for (int r = 0; r < 4; r++) iv[r] = __shfl(linv, lg * 4 + r, 16);
#pragma unroll
    for (int r = 0; r < 4; r++) {
      const int qg = qw + qb * 16 + lg * 4 + r;
#pragma unroll
      for (int dt = 0; dt < 4; dt++) {
        Ctx[((size_t)b * S_ + qg) * D_ + h * DH_ + dt * 16 + lr] =
            f2bf(ctx[qb][dt][r] * iv[r]);
      }
    }
  }
}

// ---------------------------------------------------------------- launcher
extern "C" void kernel_launch(void* const* d_in, const int* in_sizes, int n_in,
                              void* d_out, int out_size, void* d_ws, size_t ws_size,
                              hipStream_t stream) {
  const float* q   = (const float*)d_in[0];
  const float* k   = (const float*)d_in[1];
  const float* v   = (const float*)d_in[2];
  const int* mask  = (const int*)d_in[3];
  const float* q_w = (const float*)d_in[4];
  const float* q_b = (const float*)d_in[5];
  const float* k_w = (const float*)d_in[6];
  const float* k_b = (const float*)d_in[7];
  const float* v_w = (const float*)d_in[8];
  const float* v_b = (const float*)d_in[9];
  const float* o_w = (const float*)d_in[10];
  const float* o_b = (const float*)d_in[11];
  float* out = (float*)d_out;

  unsigned short* ws = (unsigned short*)d_ws;
  unsigned short* Xq = ws;
  unsigned short* Xk = Xq + NX;
  unsigned short* Xv = Xk + NX;
  unsigned short* Wq = Xv + NX;
  unsigned short* Wk = Wq + NW;
  unsigned short* Wv = Wk + NW;
  unsigned short* Wo = Wv + NW;
  unsigned short* Qp = Wo + NW;
  unsigned short* Kp = Qp + NX;
  unsigned short* Vp = Kp + NX;
  float* Ma = (float*)(Vp + NX);          // mask addend table, 4x2048 f32
  unsigned short* Vt  = Xk;  // alias: Xk dead after its GEMM
  unsigned short* Ctx = Xq;  // alias: Xq dead after its GEMM

  convert_kernel<<<dim3(6144, 8), dim3(256), 0, stream>>>(
      q, k, v, q_w, k_w, v_w, o_w, mask, Xq, Xk, Xv, Wq, Wk, Wv, Wo, Ma);

  qkv_gemm<<<dim3(64, 6, 3), dim3(256), 0, stream>>>(
      Xq, Xk, Xv, Wq, Wk, Wv, q_b, k_b, v_b, Qp, Kp, Vp);

  transpose_v<<<dim3(32, 48), dim3(256), 0, stream>>>(Vp, Vt);

  attn_kernel<<<dim3(16, 48), dim3(256), 0, stream>>>(Qp, Kp, Vt, Ma, Ctx);

  out_gemm<<<dim3(64, 6), dim3(256), 0, stream>>>(Ctx, Wo, o_b, out);
}